// Round 5
// baseline (215.481 us; speedup 1.0000x reference)
//
#include <hip/hip_runtime.h>
#include <hip/hip_bf16.h>

// Problem constants (from reference)
#define N_NODES 4096
#define IN_DIM  512
#define HID_DIM 256
#define OUT_DIM 64
#define PROP_STEP 10
#define MAX_DEG 128            // mean degree ~41; padded to multiple of 16
#define GEMM_BLOCKS 256        // MLP blocks: 16 rows each, 256 thr
#define SCAN_BLOCKS 512        // ELL scan blocks: 4 waves x 2 rows each
#define LAM_CONST (1.0f/0.9f - 1.0f)
#define SCAD_A 3.7f

__device__ __forceinline__ ushort f2bf(float f) {
    unsigned u = __float_as_uint(f);
    unsigned r = (u + 0x7FFFu + ((u >> 16) & 1u)) >> 16;  // RNE
    return (ushort)r;
}
__device__ __forceinline__ unsigned pack2(float lo, float hi) {
    return (unsigned)f2bf(lo) | ((unsigned)f2bf(hi) << 16);
}
__device__ __forceinline__ float bflo(unsigned u) { return __uint_as_float(u << 16); }
__device__ __forceinline__ float bfhi(unsigned u) { return __uint_as_float(u & 0xFFFF0000u); }
__device__ __forceinline__ float4 f4add(float4 a, float4 b) {
    return make_float4(a.x + b.x, a.y + b.y, a.z + b.z, a.w + b.w);
}

// 4 rows (AV) x 4 cols (WV) outer-product FMA into acc0..acc3
#define FMA16(AV, WV) \
    acc0.x = fmaf(AV.x, WV.x, acc0.x); acc0.y = fmaf(AV.x, WV.y, acc0.y); \
    acc0.z = fmaf(AV.x, WV.z, acc0.z); acc0.w = fmaf(AV.x, WV.w, acc0.w); \
    acc1.x = fmaf(AV.y, WV.x, acc1.x); acc1.y = fmaf(AV.y, WV.y, acc1.y); \
    acc1.z = fmaf(AV.y, WV.z, acc1.z); acc1.w = fmaf(AV.y, WV.w, acc1.w); \
    acc2.x = fmaf(AV.z, WV.x, acc2.x); acc2.y = fmaf(AV.z, WV.y, acc2.y); \
    acc2.z = fmaf(AV.z, WV.z, acc2.z); acc2.w = fmaf(AV.z, WV.w, acc2.w); \
    acc3.x = fmaf(AV.w, WV.x, acc3.x); acc3.y = fmaf(AV.w, WV.y, acc3.y); \
    acc3.z = fmaf(AV.w, WV.z, acc3.z); acc3.w = fmaf(AV.w, WV.w, acc3.w);

#define STEP(KK, WV) { float4 a_ = *(const float4*)&sF[(KK) * 16 + rg4]; FMA16(a_, WV); }

// p_i += h_i[j] * w_j over j=0..3 (16 FMA)
#define P2ROW(HV, PV) \
    PV.x = fmaf(HV.x, w0.x, PV.x); PV.y = fmaf(HV.x, w0.y, PV.y); \
    PV.z = fmaf(HV.x, w0.z, PV.z); PV.w = fmaf(HV.x, w0.w, PV.w); \
    PV.x = fmaf(HV.y, w1.x, PV.x); PV.y = fmaf(HV.y, w1.y, PV.y); \
    PV.z = fmaf(HV.y, w1.z, PV.z); PV.w = fmaf(HV.y, w1.w, PV.w); \
    PV.x = fmaf(HV.z, w2.x, PV.x); PV.y = fmaf(HV.z, w2.y, PV.y); \
    PV.z = fmaf(HV.z, w2.z, PV.z); PV.w = fmaf(HV.z, w2.w, PV.w); \
    PV.x = fmaf(HV.w, w3.x, PV.x); PV.y = fmaf(HV.w, w3.y, PV.y); \
    PV.z = fmaf(HV.w, w3.z, PV.z); PV.w = fmaf(HV.w, w3.w, PV.w);

// ---------------------------------------------------------------------------
// Fused build kernel. R4 post-mortem: VALU-busy time (11.9 us) exactly equals
// the bottom-up VALU work estimate (11.1 us/SIMD) — the 68 us duration was
// pure occupancy starvation (2 waves/SIMD, capped by 61.4 KB LDS/block).
// R5: LDS cut to 32 KB (sF stride 16; W2 read direct from L1/L2, no staging)
// and scan split into 512 light blocks dispatched FIRST -> 3 blocks/CU all
// resident (1 GEMM + 2 scan), complementary stall profiles per SIMD.
//  Blocks [0, 512): ELL build, one wave per row pair (2 rows/wave),
//    ballot+mbcnt rank, no atomics/barriers/LDS use.
//  Blocks [512, 768): MLP for 16 rows: h = relu(F@W1+b1); F0 = h@W2+b2.
//    Phase 1: F tile in LDS [k][16] (wave-uniform b128 broadcast reads);
//    W1 streamed from L1/L2, software-pipelined depth 8 in named registers.
//    Phase 2: k-split across waves, W2 direct from L1/L2, LDS reduce.
// NOTE (measured, prior session R8+R12): in-kernel grid-wide sync costs
// 55-85 us/sync on MI355X; a kernel boundary does the same visibility work
// in ~10 us. Hence per-step dispatches for propagation remain optimal.
// ---------------------------------------------------------------------------
__global__ __launch_bounds__(256, 4) void build_all(
    const float* __restrict__ A, const float* __restrict__ F,
    const float* __restrict__ W1, const float* __restrict__ b1,
    const float* __restrict__ W2, const float* __restrict__ b2,
    float* __restrict__ F0,
    int* __restrict__ ell, int* __restrict__ deg,
    float* __restrict__ invD, float* __restrict__ invDsq)
{
    __shared__ float smem[8192];   // 32 KB: sF[512][16] | sH[16][256]+sRed[3][1024]
    if (blockIdx.x >= SCAN_BLOCKS) {
        float* sF = smem;                      // [512][16] k-major
        int t  = threadIdx.x;
        int m0 = (blockIdx.x - SCAN_BLOCKS) * 16;
        // ---- stage F tile (16 rows x 512 k) into [k][row] layout, once ----
        {
            int r = t & 15, kc = (t >> 4) * 32;
            const float* src = F + (size_t)(m0 + r) * IN_DIM + kc;
#pragma unroll
            for (int j = 0; j < 8; j++) {
                float4 v = *(const float4*)(src + j * 4);
                sF[(kc + j * 4 + 0) * 16 + r] = v.x;
                sF[(kc + j * 4 + 1) * 16 + r] = v.y;
                sF[(kc + j * 4 + 2) * 16 + r] = v.z;
                sF[(kc + j * 4 + 3) * 16 + r] = v.w;
            }
        }
        __syncthreads();
        // ---- phase 1: h(16x256) = F(16x512) @ W1(512x256), 4x4 per thread ----
        int rg4 = (t >> 6) * 4;               // wave-uniform row group
        int cg  = t & 63;                      // 4-col group (lane)
        const float* Wp = W1 + cg * 4;
        float4 acc0 = {0,0,0,0}, acc1 = {0,0,0,0}, acc2 = {0,0,0,0}, acc3 = {0,0,0,0};
        float4 wa0 = *(const float4*)(Wp + 0 * HID_DIM);
        float4 wa1 = *(const float4*)(Wp + 1 * HID_DIM);
        float4 wa2 = *(const float4*)(Wp + 2 * HID_DIM);
        float4 wa3 = *(const float4*)(Wp + 3 * HID_DIM);
        float4 wb0 = *(const float4*)(Wp + 4 * HID_DIM);
        float4 wb1 = *(const float4*)(Wp + 5 * HID_DIM);
        float4 wb2 = *(const float4*)(Wp + 6 * HID_DIM);
        float4 wb3 = *(const float4*)(Wp + 7 * HID_DIM);
        for (int kb = 0; kb < IN_DIM; kb += 8) {
            STEP(kb + 0, wa0) STEP(kb + 1, wa1) STEP(kb + 2, wa2) STEP(kb + 3, wa3)
            if (kb + 8 < IN_DIM) {
                const float* wn = Wp + (size_t)(kb + 8) * HID_DIM;
                wa0 = *(const float4*)(wn);
                wa1 = *(const float4*)(wn + HID_DIM);
                wa2 = *(const float4*)(wn + 2 * HID_DIM);
                wa3 = *(const float4*)(wn + 3 * HID_DIM);
            }
            STEP(kb + 4, wb0) STEP(kb + 5, wb1) STEP(kb + 6, wb2) STEP(kb + 7, wb3)
            if (kb + 8 < IN_DIM) {
                const float* wn = Wp + (size_t)(kb + 12) * HID_DIM;
                wb0 = *(const float4*)(wn);
                wb1 = *(const float4*)(wn + HID_DIM);
                wb2 = *(const float4*)(wn + 2 * HID_DIM);
                wb3 = *(const float4*)(wn + 3 * HID_DIM);
            }
        }
        __syncthreads();                       // all sF reads done; smem reused below
        // ---- relu + bias, write h to sH[16][256] row-major ----
        float* sH   = smem;                    // 4096 floats
        float* sRed = smem + 4096;             // 3 x 1024 floats
        {
            float4 bv = *(const float4*)(b1 + cg * 4);
            float4 h0 = make_float4(fmaxf(acc0.x + bv.x, 0.f), fmaxf(acc0.y + bv.y, 0.f),
                                    fmaxf(acc0.z + bv.z, 0.f), fmaxf(acc0.w + bv.w, 0.f));
            float4 h1 = make_float4(fmaxf(acc1.x + bv.x, 0.f), fmaxf(acc1.y + bv.y, 0.f),
                                    fmaxf(acc1.z + bv.z, 0.f), fmaxf(acc1.w + bv.w, 0.f));
            float4 h2 = make_float4(fmaxf(acc2.x + bv.x, 0.f), fmaxf(acc2.y + bv.y, 0.f),
                                    fmaxf(acc2.z + bv.z, 0.f), fmaxf(acc2.w + bv.w, 0.f));
            float4 h3 = make_float4(fmaxf(acc3.x + bv.x, 0.f), fmaxf(acc3.y + bv.y, 0.f),
                                    fmaxf(acc3.z + bv.z, 0.f), fmaxf(acc3.w + bv.w, 0.f));
            *(float4*)&sH[(rg4 + 0) * 256 + cg * 4] = h0;
            *(float4*)&sH[(rg4 + 1) * 256 + cg * 4] = h1;
            *(float4*)&sH[(rg4 + 2) * 256 + cg * 4] = h2;
            *(float4*)&sH[(rg4 + 3) * 256 + cg * 4] = h3;
        }
        __syncthreads();
        // ---- phase 2: F0(16x64) = relu(h) @ W2(256x64) + b2 ----
        // k-split across waves; W2 read direct from L1/L2 (64 KB, resident).
        int lane = t & 63, wid = t >> 6;
        int rgrp = lane >> 4;                  // 4 rows: rgrp*4+i
        int cg2  = lane & 15;                  // cols cg2*4
        float4 p0 = {0,0,0,0}, p1 = {0,0,0,0}, p2 = {0,0,0,0}, p3 = {0,0,0,0};
        int kbase = wid * 64;
        for (int kq = 0; kq < 64; kq += 4) {
            int kg = kbase + kq;
            float4 h0 = *(const float4*)&sH[(rgrp * 4 + 0) * 256 + kg];
            float4 h1 = *(const float4*)&sH[(rgrp * 4 + 1) * 256 + kg];
            float4 h2 = *(const float4*)&sH[(rgrp * 4 + 2) * 256 + kg];
            float4 h3 = *(const float4*)&sH[(rgrp * 4 + 3) * 256 + kg];
            float4 w0 = *(const float4*)(W2 + (size_t)(kg + 0) * OUT_DIM + cg2 * 4);
            float4 w1 = *(const float4*)(W2 + (size_t)(kg + 1) * OUT_DIM + cg2 * 4);
            float4 w2 = *(const float4*)(W2 + (size_t)(kg + 2) * OUT_DIM + cg2 * 4);
            float4 w3 = *(const float4*)(W2 + (size_t)(kg + 3) * OUT_DIM + cg2 * 4);
            P2ROW(h0, p0) P2ROW(h1, p1) P2ROW(h2, p2) P2ROW(h3, p3)
        }
        __syncthreads();                       // sH reads done before sRed writes
        // cross-wave reduce (4 partials per output) via LDS
        if (wid) {
            float* dst = sRed + (size_t)(wid - 1) * 1024 + lane * 16;
            *(float4*)(dst + 0)  = p0; *(float4*)(dst + 4)  = p1;
            *(float4*)(dst + 8)  = p2; *(float4*)(dst + 12) = p3;
        }
        __syncthreads();
        if (wid == 0) {
#pragma unroll
            for (int w = 0; w < 3; w++) {
                const float* s = sRed + (size_t)w * 1024 + lane * 16;
                p0 = f4add(p0, *(const float4*)(s + 0));
                p1 = f4add(p1, *(const float4*)(s + 4));
                p2 = f4add(p2, *(const float4*)(s + 8));
                p3 = f4add(p3, *(const float4*)(s + 12));
            }
            float4 b2v = *(const float4*)(b2 + cg2 * 4);
            float* o = F0 + (size_t)(m0 + rgrp * 4) * OUT_DIM + cg2 * 4;
            *(float4*)(o + 0 * OUT_DIM) = f4add(p0, b2v);
            *(float4*)(o + 1 * OUT_DIM) = f4add(p1, b2v);
            *(float4*)(o + 2 * OUT_DIM) = f4add(p2, b2v);
            *(float4*)(o + 3 * OUT_DIM) = f4add(p3, b2v);
        }
    } else {
        int sb   = blockIdx.x;                        // 0..511 (scan first: HBM head start)
        int lane = threadIdx.x & 63;
        int wid  = threadIdx.x >> 6;
        int w    = sb * 4 + wid;                      // global wave 0..2047
        for (int rr = 0; rr < 2; rr++) {
            int row = w * 2 + rr;
            const float* Arow = A + (size_t)row * N_NODES;
            float4 ch[16];
#pragma unroll
            for (int c = 0; c < 16; c++)
                ch[c] = *(const float4*)(Arow + c * 256 + lane * 4);
            int* rdst = ell + (size_t)row * MAX_DEG;
            unsigned cnt = 0;                          // wave-uniform running base
#pragma unroll
            for (int c = 0; c < 16; c++) {
                float4 v = ch[c];
                int colbase = c * 256 + lane * 4;
#pragma unroll
                for (int q = 0; q < 4; q++) {
                    float vv = (q == 0) ? v.x : (q == 1) ? v.y : (q == 2) ? v.z : v.w;
                    bool nz = (vv != 0.0f);
                    unsigned long long m = __ballot(nz);
                    unsigned rank = __builtin_amdgcn_mbcnt_hi(
                        (unsigned)(m >> 32),
                        __builtin_amdgcn_mbcnt_lo((unsigned)m, 0u));
                    unsigned pos = cnt + rank;
                    if (nz && pos < MAX_DEG) rdst[pos] = colbase + q;
                    cnt += (unsigned)__popcll(m);
                }
            }
            int c  = (cnt > MAX_DEG) ? MAX_DEG : (int)cnt;
            int pad = (c + 15) & ~15;
            if (pad > MAX_DEG) pad = MAX_DEG;
            if (lane >= c && lane < pad) rdst[lane] = row;          // self pad, masked later
            int l2 = lane + 64;
            if (l2 >= c && l2 < pad) rdst[l2] = row;
            if (lane == 0) {
                deg[row] = c;
                float d = (float)(cnt + 1);   // true degree + self loop
                invD[row] = 1.0f / d;
                invDsq[row] = rsqrtf(d);
            }
        }
    }
}

// ---------------------------------------------------------------------------
// Step-0 propagation straight from fp32 F0: computes own and neighbor
// cosine-norms on the fly (shared shuffle-reduce), so no separate
// normalize/pack kernel is needed. Writes packed bf16 Fu + nrm for step 1.
// ---------------------------------------------------------------------------
__global__ __launch_bounds__(256, 4) void propagate_f0(
    const float* __restrict__ F0,
    const int* __restrict__ ell, const int* __restrict__ deg,
    const float* __restrict__ invD, const float* __restrict__ invDsq,
    const float* __restrict__ raw_gamma,
    unsigned* __restrict__ Pout, float* __restrict__ nrmOut)
{
    int lane = threadIdx.x & 63;
    int wid  = threadIdx.x >> 6;
    int r    = __builtin_amdgcn_readfirstlane(blockIdx.x * 4 + wid);
    int g    = lane >> 3;
    int sl   = lane & 7;
    const float inv_am1 = 1.0f / (SCAD_A - 1.0f);

    float gamma = 2.0f / (1.0f + expf(-raw_gamma[0]));
    float lam_k = fmaxf(gamma / SCAD_A, 1e-8f);
    float tt    = SCAD_A * lam_k;

    int dg = deg[r];
    int pad = (dg + 15) & ~15;
    int npair = pad >> 4;
    const int* nb = ell + (size_t)r * MAX_DEG;
    int ed0 = (lane < pad)      ? nb[lane]      : r;
    int ed1 = (64 + lane < pad) ? nb[64 + lane] : r;

    float iDs = invDsq[r];
    const float4* f04 = (const float4*)(F0 + (size_t)r * OUT_DIM + sl * 8);
    float4 fa = f04[0], fb = f04[1];
    float f0v[8] = { fa.x, fa.y, fa.z, fa.w, fb.x, fb.y, fb.z, fb.w };
    float ui[8];
    float ssr = 0.0f;
#pragma unroll
    for (int q = 0; q < 8; q++) { ui[q] = f0v[q] * iDs; ssr += ui[q] * ui[q]; }
    ssr += __shfl_xor(ssr, 1, 64);
    ssr += __shfl_xor(ssr, 2, 64);
    ssr += __shfl_xor(ssr, 4, 64);
    float inv_nr = 1.0f / fmaxf(sqrtf(ssr), 1e-12f);
#pragma unroll
    for (int q = 0; q < 8; q++) ui[q] *= inv_nr;

    float acc[8] = {};
    float qsum = 0.0f;
    for (int it = 0; it < npair; ++it) {
        int e0 = it * 16 + g, e1 = e0 + 8;
        int src = (it < 4) ? ed0 : ed1;
        int j0 = __shfl(src, e0 & 63, 64);
        int j1 = __shfl(src, e1 & 63, 64);
        const float4* p0 = (const float4*)(F0 + (size_t)j0 * OUT_DIM + sl * 8);
        const float4* p1 = (const float4*)(F0 + (size_t)j1 * OUT_DIM + sl * 8);
        float4 x0 = p0[0], x1 = p0[1];
        float4 y0 = p1[0], y1 = p1[1];
        float d0 = invDsq[j0], d1 = invDsq[j1];
        float v0[8] = { x0.x*d0, x0.y*d0, x0.z*d0, x0.w*d0, x1.x*d0, x1.y*d0, x1.z*d0, x1.w*d0 };
        float v1[8] = { y0.x*d1, y0.y*d1, y0.z*d1, y0.w*d1, y1.x*d1, y1.y*d1, y1.z*d1, y1.w*d1 };
        float pa = 0.f, pb = 0.f, s0 = 0.f, s1 = 0.f;
#pragma unroll
        for (int q = 0; q < 8; q++) {
            pa += ui[q] * v0[q]; s0 += v0[q] * v0[q];
            pb += ui[q] * v1[q]; s1 += v1[q] * v1[q];
        }
        pa += __shfl_xor(pa, 1, 64); pb += __shfl_xor(pb, 1, 64);
        s0 += __shfl_xor(s0, 1, 64); s1 += __shfl_xor(s1, 1, 64);
        pa += __shfl_xor(pa, 2, 64); pb += __shfl_xor(pb, 2, 64);
        s0 += __shfl_xor(s0, 2, 64); s1 += __shfl_xor(s1, 2, 64);
        pa += __shfl_xor(pa, 4, 64); pb += __shfl_xor(pb, 4, 64);
        s0 += __shfl_xor(s0, 4, 64); s1 += __shfl_xor(s1, 4, 64);
        float n0 = fmaxf(sqrtf(s0), 1e-12f);
        float n1 = fmaxf(sqrtf(s1), 1e-12f);
        float ya = 1.0f - pa / n0, yb = 1.0f - pb / n1;
        float wa = (ya <= lam_k) ? 1.0f : ((ya <= tt) ? (tt - ya) * inv_am1 / ya : 0.0f);
        float wb = (yb <= lam_k) ? 1.0f : ((yb <= tt) ? (tt - yb) * inv_am1 / yb : 0.0f);
        if (e0 >= dg) wa = 0.0f;
        if (e1 >= dg) wb = 0.0f;
        qsum += wa + wb;
#pragma unroll
        for (int q = 0; q < 8; q++) acc[q] += wa * v0[q] + wb * v1[q];
    }

#pragma unroll
    for (int off = 8; off <= 32; off <<= 1) {
#pragma unroll
        for (int q = 0; q < 8; q++) acc[q] += __shfl_xor(acc[q], off, 64);
        qsum += __shfl_xor(qsum, off, 64);
    }

    float Qh  = qsum * invD[r] + LAM_CONST;
    float rQh = 1.0f / Qh;
    float res[8], fn[8];
    float ssq = 0.0f;
#pragma unroll
    for (int q = 0; q < 8; q++) {
        res[q] = (acc[q] * iDs + LAM_CONST * f0v[q]) * rQh;
        fn[q]  = res[q] * iDs;
        ssq   += fn[q] * fn[q];
    }
    ssq += __shfl_xor(ssq, 1, 64);
    ssq += __shfl_xor(ssq, 2, 64);
    ssq += __shfl_xor(ssq, 4, 64);
    float nrm = fmaxf(sqrtf(ssq), 1e-12f);
    float inv_n = 1.0f / nrm;
    if (lane < 8) {
        uint4 fuPk;
        fuPk.x = pack2(fn[0] * inv_n, fn[1] * inv_n);
        fuPk.y = pack2(fn[2] * inv_n, fn[3] * inv_n);
        fuPk.z = pack2(fn[4] * inv_n, fn[5] * inv_n);
        fuPk.w = pack2(fn[6] * inv_n, fn[7] * inv_n);
        *(uint4*)(Pout + (size_t)r * 32 + sl * 4) = fuPk;
    }
    if (lane == 0) nrmOut[r] = nrm;
}

// ---------------------------------------------------------------------------
// Steps 1..9: packed bf16 gather path with a 2-deep register double-buffer
// (named A/B, no runtime-indexed arrays) so the next edge pair's L2 gathers
// are in flight under the current pair's ~100 VALU ops.
// ---------------------------------------------------------------------------
__global__ __launch_bounds__(256, 4) void propagate(
    const unsigned* __restrict__ Pin, const float* __restrict__ nrmIn,
    const float* __restrict__ F0,
    const int* __restrict__ ell, const int* __restrict__ deg,
    const float* __restrict__ invD, const float* __restrict__ invDsq,
    const float* __restrict__ raw_gamma, int step,
    unsigned* __restrict__ Pout, float* __restrict__ nrmOut,
    float* __restrict__ FcOut, int writeNext, int writeOut)
{
    int lane = threadIdx.x & 63;
    int wid  = threadIdx.x >> 6;
    int r    = __builtin_amdgcn_readfirstlane(blockIdx.x * 4 + wid);
    int g    = lane >> 3;              // edge group 0..7
    int sl   = lane & 7;               // feature slice
    const float inv_am1 = 1.0f / (SCAD_A - 1.0f);

    float gamma = 2.0f / (1.0f + expf(-raw_gamma[step]));
    float lam_k = fmaxf(gamma / SCAD_A, 1e-8f);
    float tt    = SCAD_A * lam_k;

    int dg = deg[r];
    int pad = (dg + 15) & ~15;
    int npair = pad >> 4;
    const int* nb = ell + (size_t)r * MAX_DEG;
    int ed0 = (lane < pad)      ? nb[lane]      : r;
    int ed1 = (64 + lane < pad) ? nb[64 + lane] : r;

    uint4 up = *(const uint4*)(Pin + (size_t)r * 32 + sl * 4);
    float ui[8] = { bflo(up.x), bfhi(up.x), bflo(up.y), bfhi(up.y),
                    bflo(up.z), bfhi(up.z), bflo(up.w), bfhi(up.w) };

    float acc[8] = {};
    float qsum = 0.0f;

    auto eidx = [&](int it_, int& J0, int& J1) {
        int e0_ = it_ * 16 + g;
        int src = (it_ < 4) ? ed0 : ed1;
        J0 = __shfl(src, e0_ & 63, 64);
        J1 = __shfl(src, (e0_ + 8) & 63, 64);
    };
    auto body = [&](int it_, uint4 U0, uint4 U1, float NR0, float NR1) {
        float pa = ui[0] * bflo(U0.x) + ui[1] * bfhi(U0.x) + ui[2] * bflo(U0.y) + ui[3] * bfhi(U0.y)
                 + ui[4] * bflo(U0.z) + ui[5] * bfhi(U0.z) + ui[6] * bflo(U0.w) + ui[7] * bfhi(U0.w);
        float pb = ui[0] * bflo(U1.x) + ui[1] * bfhi(U1.x) + ui[2] * bflo(U1.y) + ui[3] * bfhi(U1.y)
                 + ui[4] * bflo(U1.z) + ui[5] * bfhi(U1.z) + ui[6] * bflo(U1.w) + ui[7] * bfhi(U1.w);
        pa += __shfl_xor(pa, 1, 64); pb += __shfl_xor(pb, 1, 64);
        pa += __shfl_xor(pa, 2, 64); pb += __shfl_xor(pb, 2, 64);
        pa += __shfl_xor(pa, 4, 64); pb += __shfl_xor(pb, 4, 64);
        float ya = 1.0f - pa, yb = 1.0f - pb;
        float wa = (ya <= lam_k) ? 1.0f : ((ya <= tt) ? (tt - ya) * inv_am1 / ya : 0.0f);
        float wb = (yb <= lam_k) ? 1.0f : ((yb <= tt) ? (tt - yb) * inv_am1 / yb : 0.0f);
        int e0_ = it_ * 16 + g;
        if (e0_ >= dg)     wa = 0.0f;
        if (e0_ + 8 >= dg) wb = 0.0f;
        qsum += wa + wb;                             // Q_hat uses unscaled w
        float wsa = wa * NR0;                        // Fn[j] = Fu[j]*nrm[j]
        float wsb = wb * NR1;
        acc[0] += wsa * bflo(U0.x) + wsb * bflo(U1.x);
        acc[1] += wsa * bfhi(U0.x) + wsb * bfhi(U1.x);
        acc[2] += wsa * bflo(U0.y) + wsb * bflo(U1.y);
        acc[3] += wsa * bfhi(U0.y) + wsb * bfhi(U1.y);
        acc[4] += wsa * bflo(U0.z) + wsb * bflo(U1.z);
        acc[5] += wsa * bfhi(U0.z) + wsb * bfhi(U1.z);
        acc[6] += wsa * bflo(U0.w) + wsb * bflo(U1.w);
        acc[7] += wsa * bfhi(U0.w) + wsb * bfhi(U1.w);
    };

    if (npair > 0) {
        uint4 uA0, uA1, uB0, uB1;
        float nA0, nA1, nB0, nB1;
        int j0, j1;
        eidx(0, j0, j1);
        uA0 = *(const uint4*)(Pin + (size_t)j0 * 32 + sl * 4);
        uA1 = *(const uint4*)(Pin + (size_t)j1 * 32 + sl * 4);
        nA0 = nrmIn[j0]; nA1 = nrmIn[j1];
        int it = 0;
        while (true) {
            if (it + 1 < npair) {
                eidx(it + 1, j0, j1);
                uB0 = *(const uint4*)(Pin + (size_t)j0 * 32 + sl * 4);
                uB1 = *(const uint4*)(Pin + (size_t)j1 * 32 + sl * 4);
                nB0 = nrmIn[j0]; nB1 = nrmIn[j1];
            }
            body(it, uA0, uA1, nA0, nA1);
            ++it; if (it >= npair) break;
            if (it + 1 < npair) {
                eidx(it + 1, j0, j1);
                uA0 = *(const uint4*)(Pin + (size_t)j0 * 32 + sl * 4);
                uA1 = *(const uint4*)(Pin + (size_t)j1 * 32 + sl * 4);
                nA0 = nrmIn[j0]; nA1 = nrmIn[j1];
            }
            body(it, uB0, uB1, nB0, nB1);
            ++it; if (it >= npair) break;
        }
    }

    // cross-group reduction: every lane ends with the full row sums
#pragma unroll
    for (int off = 8; off <= 32; off <<= 1) {
#pragma unroll
        for (int q = 0; q < 8; q++) acc[q] += __shfl_xor(acc[q], off, 64);
        qsum += __shfl_xor(qsum, off, 64);
    }

    float iDs = invDsq[r];
    float Qh  = qsum * invD[r] + LAM_CONST;
    float rQh = 1.0f / Qh;
    const float4* f04 = (const float4*)(F0 + (size_t)r * OUT_DIM + sl * 8);
    float4 f0a = f04[0], f0b = f04[1];
    float f0v[8] = { f0a.x, f0a.y, f0a.z, f0a.w, f0b.x, f0b.y, f0b.z, f0b.w };
    float res[8];
#pragma unroll
    for (int q = 0; q < 8; q++) res[q] = (acc[q] * iDs + LAM_CONST * f0v[q]) * rQh;

    if (writeOut && lane < 8) {
        float4* o4 = (float4*)(FcOut + (size_t)r * OUT_DIM + sl * 8);
        o4[0] = make_float4(res[0], res[1], res[2], res[3]);
        o4[1] = make_float4(res[4], res[5], res[6], res[7]);
    }
    if (writeNext) {
        float fn[8];
        float ssq = 0.0f;
#pragma unroll
        for (int q = 0; q < 8; q++) { fn[q] = res[q] * iDs; ssq += fn[q] * fn[q]; }
        ssq += __shfl_xor(ssq, 1, 64);   // lanes 0..7 mix among themselves
        ssq += __shfl_xor(ssq, 2, 64);
        ssq += __shfl_xor(ssq, 4, 64);
        float nrm = fmaxf(sqrtf(ssq), 1e-12f);
        float inv_n = 1.0f / nrm;
        if (lane < 8) {
            uint4 fuPk;
            fuPk.x = pack2(fn[0] * inv_n, fn[1] * inv_n);
            fuPk.y = pack2(fn[2] * inv_n, fn[3] * inv_n);
            fuPk.z = pack2(fn[4] * inv_n, fn[5] * inv_n);
            fuPk.w = pack2(fn[6] * inv_n, fn[7] * inv_n);
            *(uint4*)(Pout + (size_t)r * 32 + sl * 4) = fuPk;
        }
        if (lane == 0) nrmOut[r] = nrm;
    }
}

// ---------------------------------------------------------------------------
extern "C" void kernel_launch(void* const* d_in, const int* in_sizes, int n_in,
                              void* d_out, int out_size, void* d_ws, size_t ws_size,
                              hipStream_t stream)
{
    const float* A  = (const float*)d_in[0];
    const float* F  = (const float*)d_in[1];
    const float* W1 = (const float*)d_in[2];
    const float* b1 = (const float*)d_in[3];
    const float* W2 = (const float*)d_in[4];
    const float* b2 = (const float*)d_in[5];
    const float* rg = (const float*)d_in[6];
    float* out = (float*)d_out;

    // workspace layout (~4.6 MB)
    char* p = (char*)d_ws;
    float* F0     = (float*)p; p += (size_t)N_NODES * OUT_DIM * 4;           // 1 MB
    unsigned* Pa  = (unsigned*)p; p += (size_t)N_NODES * 32 * 4;             // 512 KB packed Fu
    unsigned* Pb  = (unsigned*)p; p += (size_t)N_NODES * 32 * 4;             // 512 KB
    float* nrmA   = (float*)p; p += (size_t)N_NODES * 4;                     // 16 KB
    float* nrmB   = (float*)p; p += (size_t)N_NODES * 4;
    float* invD   = (float*)p; p += (size_t)N_NODES * 4;
    float* invDsq = (float*)p; p += (size_t)N_NODES * 4;
    int*   deg    = (int*)p;   p += (size_t)N_NODES * 4;
    int*   ell    = (int*)p;   p += (size_t)N_NODES * MAX_DEG * 4;           // 2 MB

    build_all<<<GEMM_BLOCKS + SCAN_BLOCKS, 256, 0, stream>>>(
        A, F, W1, b1, W2, b2, F0, ell, deg, invD, invDsq);

    // step 0 straight from fp32 F0 (writes Pa/nrmA)
    propagate_f0<<<N_NODES / 4, 256, 0, stream>>>(
        F0, ell, deg, invD, invDsq, rg, Pa, nrmA);

    for (int k = 1; k < PROP_STEP; k++) {
        unsigned* Pin   = (k & 1) ? Pa : Pb;
        unsigned* Pout  = (k & 1) ? Pb : Pa;
        float* nIn      = (k & 1) ? nrmA : nrmB;
        float* nOut     = (k & 1) ? nrmB : nrmA;
        int last = (k == PROP_STEP - 1);
        propagate<<<N_NODES / 4, 256, 0, stream>>>(
            Pin, nIn, F0, ell, deg, invD, invDsq, rg, k,
            Pout, nOut, out, !last, last);
    }
}

// Round 6
// 195.469 us; speedup vs baseline: 1.1024x; 1.1024x over previous
//
#include <hip/hip_runtime.h>
#include <hip/hip_bf16.h>

// Problem constants (from reference)
#define N_NODES 4096
#define IN_DIM  512
#define HID_DIM 256
#define OUT_DIM 64
#define PROP_STEP 10
#define MAX_DEG 128            // mean degree ~41; padded to multiple of 16
#define GEMM_BLOCKS 512        // MLP blocks: 8 rows each, K split 4x across waves
#define SCAN_BLOCKS 512        // ELL scan blocks: 4 waves x 2 rows each
#define LAM_CONST (1.0f/0.9f - 1.0f)
#define SCAD_A 3.7f

__device__ __forceinline__ ushort f2bf(float f) {
    unsigned u = __float_as_uint(f);
    unsigned r = (u + 0x7FFFu + ((u >> 16) & 1u)) >> 16;  // RNE
    return (ushort)r;
}
__device__ __forceinline__ unsigned pack2(float lo, float hi) {
    return (unsigned)f2bf(lo) | ((unsigned)f2bf(hi) << 16);
}
__device__ __forceinline__ float bflo(unsigned u) { return __uint_as_float(u << 16); }
__device__ __forceinline__ float bfhi(unsigned u) { return __uint_as_float(u & 0xFFFF0000u); }
__device__ __forceinline__ float4 f4add(float4 a, float4 b) {
    return make_float4(a.x + b.x, a.y + b.y, a.z + b.z, a.w + b.w);
}

// 8 rows (a0 lanes .x-.w = rows 0-3, a1 = rows 4-7) x 4 cols (WV) -> ac0..ac7
#define FMA32(A0, A1, WV) \
    ac0.x = fmaf(A0.x, WV.x, ac0.x); ac0.y = fmaf(A0.x, WV.y, ac0.y); \
    ac0.z = fmaf(A0.x, WV.z, ac0.z); ac0.w = fmaf(A0.x, WV.w, ac0.w); \
    ac1.x = fmaf(A0.y, WV.x, ac1.x); ac1.y = fmaf(A0.y, WV.y, ac1.y); \
    ac1.z = fmaf(A0.y, WV.z, ac1.z); ac1.w = fmaf(A0.y, WV.w, ac1.w); \
    ac2.x = fmaf(A0.z, WV.x, ac2.x); ac2.y = fmaf(A0.z, WV.y, ac2.y); \
    ac2.z = fmaf(A0.z, WV.z, ac2.z); ac2.w = fmaf(A0.z, WV.w, ac2.w); \
    ac3.x = fmaf(A0.w, WV.x, ac3.x); ac3.y = fmaf(A0.w, WV.y, ac3.y); \
    ac3.z = fmaf(A0.w, WV.z, ac3.z); ac3.w = fmaf(A0.w, WV.w, ac3.w); \
    ac4.x = fmaf(A1.x, WV.x, ac4.x); ac4.y = fmaf(A1.x, WV.y, ac4.y); \
    ac4.z = fmaf(A1.x, WV.z, ac4.z); ac4.w = fmaf(A1.x, WV.w, ac4.w); \
    ac5.x = fmaf(A1.y, WV.x, ac5.x); ac5.y = fmaf(A1.y, WV.y, ac5.y); \
    ac5.z = fmaf(A1.y, WV.z, ac5.z); ac5.w = fmaf(A1.y, WV.w, ac5.w); \
    ac6.x = fmaf(A1.z, WV.x, ac6.x); ac6.y = fmaf(A1.z, WV.y, ac6.y); \
    ac6.z = fmaf(A1.z, WV.z, ac6.z); ac6.w = fmaf(A1.z, WV.w, ac6.w); \
    ac7.x = fmaf(A1.w, WV.x, ac7.x); ac7.y = fmaf(A1.w, WV.y, ac7.y); \
    ac7.z = fmaf(A1.w, WV.z, ac7.z); ac7.w = fmaf(A1.w, WV.w, ac7.w);

// consume one k with W fragment WV (sF broadcast reads are wave-uniform)
#define CONS(KK, WV) { \
    float4 a0_ = *(const float4*)&sF[(KK) * 8];     \
    float4 a1_ = *(const float4*)&sF[(KK) * 8 + 4]; \
    FMA32(a0_, a1_, WV) }

// p_i += h_i[j] * w_j over j=0..3 (16 FMA)
#define P2ROW(HV, PV) \
    PV.x = fmaf(HV.x, w0.x, PV.x); PV.y = fmaf(HV.x, w0.y, PV.y); \
    PV.z = fmaf(HV.x, w0.z, PV.z); PV.w = fmaf(HV.x, w0.w, PV.w); \
    PV.x = fmaf(HV.y, w1.x, PV.x); PV.y = fmaf(HV.y, w1.y, PV.y); \
    PV.z = fmaf(HV.y, w1.z, PV.z); PV.w = fmaf(HV.y, w1.w, PV.w); \
    PV.x = fmaf(HV.z, w2.x, PV.x); PV.y = fmaf(HV.z, w2.y, PV.y); \
    PV.z = fmaf(HV.z, w2.z, PV.z); PV.w = fmaf(HV.z, w2.w, PV.w); \
    PV.x = fmaf(HV.w, w3.x, PV.x); PV.y = fmaf(HV.w, w3.y, PV.y); \
    PV.z = fmaf(HV.w, w3.z, PV.z); PV.w = fmaf(HV.w, w3.w, PV.w);

// ---------------------------------------------------------------------------
// Fused build kernel. R5 post-mortem: scan retires ~15us in, then the lone
// GEMM wave/SIMD runs ~45us of mostly-stall (K=512 serial chain, prefetch
// distance ~256cyc vs 200-900cyc W1 latency). Time-avg occupancy 16% matches
// that picture exactly. R6: K SPLIT 4x ACROSS WAVES (each wave K=128, 4096
// FMA, 32 FMA per W1 load) + 512 GEMM blocks of 8 rows -> 2 GEMM waves/SIMD
// co-resident with 2 scan waves/SIMD for the whole kernel (1024 blocks,
// 4/CU, 32 KB LDS each). Partial h / partial F0 reduced through LDS.
//  Blocks [0, 512): ELL build, one wave per row pair, ballot+mbcnt rank.
//  Blocks [512, 1024): 8-row MLP: h = relu(F@W1+b1); F0 = h@W2+b2.
// NOTE (measured, prior session R8+R12): in-kernel grid-wide sync costs
// 55-85 us/sync on MI355X; a kernel boundary does the same visibility work
// in ~10 us. Hence per-step dispatches for propagation remain optimal.
// ---------------------------------------------------------------------------
__global__ __launch_bounds__(256, 4) void build_all(
    const float* __restrict__ A, const float* __restrict__ F,
    const float* __restrict__ W1, const float* __restrict__ b1,
    const float* __restrict__ W2, const float* __restrict__ b2,
    float* __restrict__ F0,
    int* __restrict__ ell, int* __restrict__ deg,
    float* __restrict__ invD, float* __restrict__ invDsq)
{
    __shared__ float smem[8192];   // 32 KB
    if (blockIdx.x >= SCAN_BLOCKS) {
        float* sF = smem;                      // [512][8] k-major (16 KB)
        int t    = threadIdx.x;
        int lane = t & 63, wid = t >> 6;
        int m0   = (blockIdx.x - SCAN_BLOCKS) * 8;
        // ---- stage F tile (8 rows x 512 k) into [k][row] layout, once ----
        {
            int r = t & 7, kc = (t >> 3) * 16;
            const float* src = F + (size_t)(m0 + r) * IN_DIM + kc;
#pragma unroll
            for (int j = 0; j < 4; j++) {
                float4 v = *(const float4*)(src + j * 4);
                sF[(kc + j * 4 + 0) * 8 + r] = v.x;
                sF[(kc + j * 4 + 1) * 8 + r] = v.y;
                sF[(kc + j * 4 + 2) * 8 + r] = v.z;
                sF[(kc + j * 4 + 3) * 8 + r] = v.w;
            }
        }
        __syncthreads();
        // ---- phase 1: partial h(8x256) over this wave's K=128 slice ----
        int cg = lane;                         // 4-col group
        int kw = wid * 128;                    // wave's k base
        const float* Wp = W1 + (size_t)kw * HID_DIM + cg * 4;
        float4 ac0 = {0,0,0,0}, ac1 = {0,0,0,0}, ac2 = {0,0,0,0}, ac3 = {0,0,0,0};
        float4 ac4 = {0,0,0,0}, ac5 = {0,0,0,0}, ac6 = {0,0,0,0}, ac7 = {0,0,0,0};
        float4 wa0 = *(const float4*)(Wp + 0 * HID_DIM);
        float4 wa1 = *(const float4*)(Wp + 1 * HID_DIM);
        float4 wa2 = *(const float4*)(Wp + 2 * HID_DIM);
        float4 wa3 = *(const float4*)(Wp + 3 * HID_DIM);
        float4 wb0 = *(const float4*)(Wp + 4 * HID_DIM);
        float4 wb1 = *(const float4*)(Wp + 5 * HID_DIM);
        float4 wb2 = *(const float4*)(Wp + 6 * HID_DIM);
        float4 wb3 = *(const float4*)(Wp + 7 * HID_DIM);
        for (int kb = 0; kb < 128; kb += 8) {
            int k0 = kw + kb;
            CONS(k0 + 0, wa0) CONS(k0 + 1, wa1) CONS(k0 + 2, wa2) CONS(k0 + 3, wa3)
            if (kb + 8 < 128) {
                const float* wn = Wp + (size_t)(kb + 8) * HID_DIM;
                wa0 = *(const float4*)(wn);
                wa1 = *(const float4*)(wn + HID_DIM);
                wa2 = *(const float4*)(wn + 2 * HID_DIM);
                wa3 = *(const float4*)(wn + 3 * HID_DIM);
            }
            CONS(k0 + 4, wb0) CONS(k0 + 5, wb1) CONS(k0 + 6, wb2) CONS(k0 + 7, wb3)
            if (kb + 8 < 128) {
                const float* wn = Wp + (size_t)(kb + 12) * HID_DIM;
                wb0 = *(const float4*)(wn);
                wb1 = *(const float4*)(wn + HID_DIM);
                wb2 = *(const float4*)(wn + 2 * HID_DIM);
                wb3 = *(const float4*)(wn + 3 * HID_DIM);
            }
        }
        __syncthreads();                       // sF reads done; reuse smem
        // ---- write per-wave partials [4][8][256] (32 KB, overlays sF) ----
        {
            float* pp = smem + (size_t)wid * 2048;
            *(float4*)&pp[0 * 256 + cg * 4] = ac0;
            *(float4*)&pp[1 * 256 + cg * 4] = ac1;
            *(float4*)&pp[2 * 256 + cg * 4] = ac2;
            *(float4*)&pp[3 * 256 + cg * 4] = ac3;
            *(float4*)&pp[4 * 256 + cg * 4] = ac4;
            *(float4*)&pp[5 * 256 + cg * 4] = ac5;
            *(float4*)&pp[6 * 256 + cg * 4] = ac6;
            *(float4*)&pp[7 * 256 + cg * 4] = ac7;
        }
        __syncthreads();
        // ---- reduce partials + bias + relu -> sH[8][256] (in region 0) ----
        for (int i = t; i < 2048; i += 256) {
            float h = smem[i] + smem[i + 2048] + smem[i + 4096] + smem[i + 6144]
                    + b1[i & 255];
            smem[i] = fmaxf(h, 0.0f);
        }
        __syncthreads();
        // ---- phase 2: partial F0(8x64) over this wave's K=64 slice ----
        float* sH = smem;                      // [8][256]
        int rgrp = lane >> 4;                  // rows {rgrp*2, rgrp*2+1}
        int cg2  = lane & 15;                  // cols cg2*4
        float4 p0 = {0,0,0,0}, p1 = {0,0,0,0};
        int kbase = wid * 64;
        for (int kq = 0; kq < 64; kq += 4) {
            int kg = kbase + kq;
            float4 h0 = *(const float4*)&sH[(rgrp * 2 + 0) * 256 + kg];
            float4 h1 = *(const float4*)&sH[(rgrp * 2 + 1) * 256 + kg];
            float4 w0 = *(const float4*)(W2 + (size_t)(kg + 0) * OUT_DIM + cg2 * 4);
            float4 w1 = *(const float4*)(W2 + (size_t)(kg + 1) * OUT_DIM + cg2 * 4);
            float4 w2 = *(const float4*)(W2 + (size_t)(kg + 2) * OUT_DIM + cg2 * 4);
            float4 w3 = *(const float4*)(W2 + (size_t)(kg + 3) * OUT_DIM + cg2 * 4);
            P2ROW(h0, p0) P2ROW(h1, p1)
        }
        __syncthreads();                       // sH reads done
        if (wid) {                             // waves 1..3 park partials
            float* dst = smem + 2048 + (size_t)(wid - 1) * 512 + lane * 8;
            *(float4*)(dst + 0) = p0;
            *(float4*)(dst + 4) = p1;
        }
        __syncthreads();
        if (wid == 0) {
#pragma unroll
            for (int w = 0; w < 3; w++) {
                const float* s = smem + 2048 + (size_t)w * 512 + lane * 8;
                p0 = f4add(p0, *(const float4*)(s + 0));
                p1 = f4add(p1, *(const float4*)(s + 4));
            }
            float4 b2v = *(const float4*)(b2 + cg2 * 4);
            float* o = F0 + (size_t)(m0 + rgrp * 2) * OUT_DIM + cg2 * 4;
            *(float4*)(o + 0 * OUT_DIM) = f4add(p0, b2v);
            *(float4*)(o + 1 * OUT_DIM) = f4add(p1, b2v);
        }
    } else {
        int sb   = blockIdx.x;                        // 0..511 (scan first: HBM head start)
        int lane = threadIdx.x & 63;
        int wid  = threadIdx.x >> 6;
        int w    = sb * 4 + wid;                      // global wave 0..2047
        for (int rr = 0; rr < 2; rr++) {
            int row = w * 2 + rr;
            const float* Arow = A + (size_t)row * N_NODES;
            float4 ch[16];
#pragma unroll
            for (int c = 0; c < 16; c++)
                ch[c] = *(const float4*)(Arow + c * 256 + lane * 4);
            int* rdst = ell + (size_t)row * MAX_DEG;
            unsigned cnt = 0;                          // wave-uniform running base
#pragma unroll
            for (int c = 0; c < 16; c++) {
                float4 v = ch[c];
                int colbase = c * 256 + lane * 4;
#pragma unroll
                for (int q = 0; q < 4; q++) {
                    float vv = (q == 0) ? v.x : (q == 1) ? v.y : (q == 2) ? v.z : v.w;
                    bool nz = (vv != 0.0f);
                    unsigned long long m = __ballot(nz);
                    unsigned rank = __builtin_amdgcn_mbcnt_hi(
                        (unsigned)(m >> 32),
                        __builtin_amdgcn_mbcnt_lo((unsigned)m, 0u));
                    unsigned pos = cnt + rank;
                    if (nz && pos < MAX_DEG) rdst[pos] = colbase + q;
                    cnt += (unsigned)__popcll(m);
                }
            }
            int c  = (cnt > MAX_DEG) ? MAX_DEG : (int)cnt;
            int pad = (c + 15) & ~15;
            if (pad > MAX_DEG) pad = MAX_DEG;
            if (lane >= c && lane < pad) rdst[lane] = row;          // self pad, masked later
            int l2 = lane + 64;
            if (l2 >= c && l2 < pad) rdst[l2] = row;
            if (lane == 0) {
                deg[row] = c;
                float d = (float)(cnt + 1);   // true degree + self loop
                invD[row] = 1.0f / d;
                invDsq[row] = rsqrtf(d);
            }
        }
    }
}

// ---------------------------------------------------------------------------
// Step-0 propagation straight from fp32 F0: computes own and neighbor
// cosine-norms on the fly (shared shuffle-reduce), so no separate
// normalize/pack kernel is needed. Writes packed bf16 Fu + nrm for step 1.
// ---------------------------------------------------------------------------
__global__ __launch_bounds__(256, 4) void propagate_f0(
    const float* __restrict__ F0,
    const int* __restrict__ ell, const int* __restrict__ deg,
    const float* __restrict__ invD, const float* __restrict__ invDsq,
    const float* __restrict__ raw_gamma,
    unsigned* __restrict__ Pout, float* __restrict__ nrmOut)
{
    int lane = threadIdx.x & 63;
    int wid  = threadIdx.x >> 6;
    int r    = __builtin_amdgcn_readfirstlane(blockIdx.x * 4 + wid);
    int g    = lane >> 3;
    int sl   = lane & 7;
    const float inv_am1 = 1.0f / (SCAD_A - 1.0f);

    float gamma = 2.0f / (1.0f + expf(-raw_gamma[0]));
    float lam_k = fmaxf(gamma / SCAD_A, 1e-8f);
    float tt    = SCAD_A * lam_k;

    int dg = deg[r];
    int pad = (dg + 15) & ~15;
    int npair = pad >> 4;
    const int* nb = ell + (size_t)r * MAX_DEG;
    int ed0 = (lane < pad)      ? nb[lane]      : r;
    int ed1 = (64 + lane < pad) ? nb[64 + lane] : r;

    float iDs = invDsq[r];
    const float4* f04 = (const float4*)(F0 + (size_t)r * OUT_DIM + sl * 8);
    float4 fa = f04[0], fb = f04[1];
    float f0v[8] = { fa.x, fa.y, fa.z, fa.w, fb.x, fb.y, fb.z, fb.w };
    float ui[8];
    float ssr = 0.0f;
#pragma unroll
    for (int q = 0; q < 8; q++) { ui[q] = f0v[q] * iDs; ssr += ui[q] * ui[q]; }
    ssr += __shfl_xor(ssr, 1, 64);
    ssr += __shfl_xor(ssr, 2, 64);
    ssr += __shfl_xor(ssr, 4, 64);
    float inv_nr = 1.0f / fmaxf(sqrtf(ssr), 1e-12f);
#pragma unroll
    for (int q = 0; q < 8; q++) ui[q] *= inv_nr;

    float acc[8] = {};
    float qsum = 0.0f;
    for (int it = 0; it < npair; ++it) {
        int e0 = it * 16 + g, e1 = e0 + 8;
        int src = (it < 4) ? ed0 : ed1;
        int j0 = __shfl(src, e0 & 63, 64);
        int j1 = __shfl(src, e1 & 63, 64);
        const float4* p0 = (const float4*)(F0 + (size_t)j0 * OUT_DIM + sl * 8);
        const float4* p1 = (const float4*)(F0 + (size_t)j1 * OUT_DIM + sl * 8);
        float4 x0 = p0[0], x1 = p0[1];
        float4 y0 = p1[0], y1 = p1[1];
        float d0 = invDsq[j0], d1 = invDsq[j1];
        float v0[8] = { x0.x*d0, x0.y*d0, x0.z*d0, x0.w*d0, x1.x*d0, x1.y*d0, x1.z*d0, x1.w*d0 };
        float v1[8] = { y0.x*d1, y0.y*d1, y0.z*d1, y0.w*d1, y1.x*d1, y1.y*d1, y1.z*d1, y1.w*d1 };
        float pa = 0.f, pb = 0.f, s0 = 0.f, s1 = 0.f;
#pragma unroll
        for (int q = 0; q < 8; q++) {
            pa += ui[q] * v0[q]; s0 += v0[q] * v0[q];
            pb += ui[q] * v1[q]; s1 += v1[q] * v1[q];
        }
        pa += __shfl_xor(pa, 1, 64); pb += __shfl_xor(pb, 1, 64);
        s0 += __shfl_xor(s0, 1, 64); s1 += __shfl_xor(s1, 1, 64);
        pa += __shfl_xor(pa, 2, 64); pb += __shfl_xor(pb, 2, 64);
        s0 += __shfl_xor(s0, 2, 64); s1 += __shfl_xor(s1, 2, 64);
        pa += __shfl_xor(pa, 4, 64); pb += __shfl_xor(pb, 4, 64);
        s0 += __shfl_xor(s0, 4, 64); s1 += __shfl_xor(s1, 4, 64);
        float n0 = fmaxf(sqrtf(s0), 1e-12f);
        float n1 = fmaxf(sqrtf(s1), 1e-12f);
        float ya = 1.0f - pa / n0, yb = 1.0f - pb / n1;
        float wa = (ya <= lam_k) ? 1.0f : ((ya <= tt) ? (tt - ya) * inv_am1 / ya : 0.0f);
        float wb = (yb <= lam_k) ? 1.0f : ((yb <= tt) ? (tt - yb) * inv_am1 / yb : 0.0f);
        if (e0 >= dg) wa = 0.0f;
        if (e1 >= dg) wb = 0.0f;
        qsum += wa + wb;
#pragma unroll
        for (int q = 0; q < 8; q++) acc[q] += wa * v0[q] + wb * v1[q];
    }

#pragma unroll
    for (int off = 8; off <= 32; off <<= 1) {
#pragma unroll
        for (int q = 0; q < 8; q++) acc[q] += __shfl_xor(acc[q], off, 64);
        qsum += __shfl_xor(qsum, off, 64);
    }

    float Qh  = qsum * invD[r] + LAM_CONST;
    float rQh = 1.0f / Qh;
    float res[8], fn[8];
    float ssq = 0.0f;
#pragma unroll
    for (int q = 0; q < 8; q++) {
        res[q] = (acc[q] * iDs + LAM_CONST * f0v[q]) * rQh;
        fn[q]  = res[q] * iDs;
        ssq   += fn[q] * fn[q];
    }
    ssq += __shfl_xor(ssq, 1, 64);
    ssq += __shfl_xor(ssq, 2, 64);
    ssq += __shfl_xor(ssq, 4, 64);
    float nrm = fmaxf(sqrtf(ssq), 1e-12f);
    float inv_n = 1.0f / nrm;
    if (lane < 8) {
        uint4 fuPk;
        fuPk.x = pack2(fn[0] * inv_n, fn[1] * inv_n);
        fuPk.y = pack2(fn[2] * inv_n, fn[3] * inv_n);
        fuPk.z = pack2(fn[4] * inv_n, fn[5] * inv_n);
        fuPk.w = pack2(fn[6] * inv_n, fn[7] * inv_n);
        *(uint4*)(Pout + (size_t)r * 32 + sl * 4) = fuPk;
    }
    if (lane == 0) nrmOut[r] = nrm;
}

// ---------------------------------------------------------------------------
// Steps 1..9: packed bf16 gather path with a 2-deep register double-buffer
// (named A/B, no runtime-indexed arrays) so the next edge pair's L2 gathers
// are in flight under the current pair's ~100 VALU ops.
// ---------------------------------------------------------------------------
__global__ __launch_bounds__(256, 4) void propagate(
    const unsigned* __restrict__ Pin, const float* __restrict__ nrmIn,
    const float* __restrict__ F0,
    const int* __restrict__ ell, const int* __restrict__ deg,
    const float* __restrict__ invD, const float* __restrict__ invDsq,
    const float* __restrict__ raw_gamma, int step,
    unsigned* __restrict__ Pout, float* __restrict__ nrmOut,
    float* __restrict__ FcOut, int writeNext, int writeOut)
{
    int lane = threadIdx.x & 63;
    int wid  = threadIdx.x >> 6;
    int r    = __builtin_amdgcn_readfirstlane(blockIdx.x * 4 + wid);
    int g    = lane >> 3;              // edge group 0..7
    int sl   = lane & 7;               // feature slice
    const float inv_am1 = 1.0f / (SCAD_A - 1.0f);

    float gamma = 2.0f / (1.0f + expf(-raw_gamma[step]));
    float lam_k = fmaxf(gamma / SCAD_A, 1e-8f);
    float tt    = SCAD_A * lam_k;

    int dg = deg[r];
    int pad = (dg + 15) & ~15;
    int npair = pad >> 4;
    const int* nb = ell + (size_t)r * MAX_DEG;
    int ed0 = (lane < pad)      ? nb[lane]      : r;
    int ed1 = (64 + lane < pad) ? nb[64 + lane] : r;

    uint4 up = *(const uint4*)(Pin + (size_t)r * 32 + sl * 4);
    float ui[8] = { bflo(up.x), bfhi(up.x), bflo(up.y), bfhi(up.y),
                    bflo(up.z), bfhi(up.z), bflo(up.w), bfhi(up.w) };

    float acc[8] = {};
    float qsum = 0.0f;

    auto eidx = [&](int it_, int& J0, int& J1) {
        int e0_ = it_ * 16 + g;
        int src = (it_ < 4) ? ed0 : ed1;
        J0 = __shfl(src, e0_ & 63, 64);
        J1 = __shfl(src, (e0_ + 8) & 63, 64);
    };
    auto body = [&](int it_, uint4 U0, uint4 U1, float NR0, float NR1) {
        float pa = ui[0] * bflo(U0.x) + ui[1] * bfhi(U0.x) + ui[2] * bflo(U0.y) + ui[3] * bfhi(U0.y)
                 + ui[4] * bflo(U0.z) + ui[5] * bfhi(U0.z) + ui[6] * bflo(U0.w) + ui[7] * bfhi(U0.w);
        float pb = ui[0] * bflo(U1.x) + ui[1] * bfhi(U1.x) + ui[2] * bflo(U1.y) + ui[3] * bfhi(U1.y)
                 + ui[4] * bflo(U1.z) + ui[5] * bfhi(U1.z) + ui[6] * bflo(U1.w) + ui[7] * bfhi(U1.w);
        pa += __shfl_xor(pa, 1, 64); pb += __shfl_xor(pb, 1, 64);
        pa += __shfl_xor(pa, 2, 64); pb += __shfl_xor(pb, 2, 64);
        pa += __shfl_xor(pa, 4, 64); pb += __shfl_xor(pb, 4, 64);
        float ya = 1.0f - pa, yb = 1.0f - pb;
        float wa = (ya <= lam_k) ? 1.0f : ((ya <= tt) ? (tt - ya) * inv_am1 / ya : 0.0f);
        float wb = (yb <= lam_k) ? 1.0f : ((yb <= tt) ? (tt - yb) * inv_am1 / yb : 0.0f);
        int e0_ = it_ * 16 + g;
        if (e0_ >= dg)     wa = 0.0f;
        if (e0_ + 8 >= dg) wb = 0.0f;
        qsum += wa + wb;                             // Q_hat uses unscaled w
        float wsa = wa * NR0;                        // Fn[j] = Fu[j]*nrm[j]
        float wsb = wb * NR1;
        acc[0] += wsa * bflo(U0.x) + wsb * bflo(U1.x);
        acc[1] += wsa * bfhi(U0.x) + wsb * bfhi(U1.x);
        acc[2] += wsa * bflo(U0.y) + wsb * bflo(U1.y);
        acc[3] += wsa * bfhi(U0.y) + wsb * bfhi(U1.y);
        acc[4] += wsa * bflo(U0.z) + wsb * bflo(U1.z);
        acc[5] += wsa * bfhi(U0.z) + wsb * bfhi(U1.z);
        acc[6] += wsa * bflo(U0.w) + wsb * bflo(U1.w);
        acc[7] += wsa * bfhi(U0.w) + wsb * bfhi(U1.w);
    };

    if (npair > 0) {
        uint4 uA0, uA1, uB0, uB1;
        float nA0, nA1, nB0, nB1;
        int j0, j1;
        eidx(0, j0, j1);
        uA0 = *(const uint4*)(Pin + (size_t)j0 * 32 + sl * 4);
        uA1 = *(const uint4*)(Pin + (size_t)j1 * 32 + sl * 4);
        nA0 = nrmIn[j0]; nA1 = nrmIn[j1];
        int it = 0;
        while (true) {
            if (it + 1 < npair) {
                eidx(it + 1, j0, j1);
                uB0 = *(const uint4*)(Pin + (size_t)j0 * 32 + sl * 4);
                uB1 = *(const uint4*)(Pin + (size_t)j1 * 32 + sl * 4);
                nB0 = nrmIn[j0]; nB1 = nrmIn[j1];
            }
            body(it, uA0, uA1, nA0, nA1);
            ++it; if (it >= npair) break;
            if (it + 1 < npair) {
                eidx(it + 1, j0, j1);
                uA0 = *(const uint4*)(Pin + (size_t)j0 * 32 + sl * 4);
                uA1 = *(const uint4*)(Pin + (size_t)j1 * 32 + sl * 4);
                nA0 = nrmIn[j0]; nA1 = nrmIn[j1];
            }
            body(it, uB0, uB1, nB0, nB1);
            ++it; if (it >= npair) break;
        }
    }

    // cross-group reduction: every lane ends with the full row sums
#pragma unroll
    for (int off = 8; off <= 32; off <<= 1) {
#pragma unroll
        for (int q = 0; q < 8; q++) acc[q] += __shfl_xor(acc[q], off, 64);
        qsum += __shfl_xor(qsum, off, 64);
    }

    float iDs = invDsq[r];
    float Qh  = qsum * invD[r] + LAM_CONST;
    float rQh = 1.0f / Qh;
    const float4* f04 = (const float4*)(F0 + (size_t)r * OUT_DIM + sl * 8);
    float4 f0a = f04[0], f0b = f04[1];
    float f0v[8] = { f0a.x, f0a.y, f0a.z, f0a.w, f0b.x, f0b.y, f0b.z, f0b.w };
    float res[8];
#pragma unroll
    for (int q = 0; q < 8; q++) res[q] = (acc[q] * iDs + LAM_CONST * f0v[q]) * rQh;

    if (writeOut && lane < 8) {
        float4* o4 = (float4*)(FcOut + (size_t)r * OUT_DIM + sl * 8);
        o4[0] = make_float4(res[0], res[1], res[2], res[3]);
        o4[1] = make_float4(res[4], res[5], res[6], res[7]);
    }
    if (writeNext) {
        float fn[8];
        float ssq = 0.0f;
#pragma unroll
        for (int q = 0; q < 8; q++) { fn[q] = res[q] * iDs; ssq += fn[q] * fn[q]; }
        ssq += __shfl_xor(ssq, 1, 64);   // lanes 0..7 mix among themselves
        ssq += __shfl_xor(ssq, 2, 64);
        ssq += __shfl_xor(ssq, 4, 64);
        float nrm = fmaxf(sqrtf(ssq), 1e-12f);
        float inv_n = 1.0f / nrm;
        if (lane < 8) {
            uint4 fuPk;
            fuPk.x = pack2(fn[0] * inv_n, fn[1] * inv_n);
            fuPk.y = pack2(fn[2] * inv_n, fn[3] * inv_n);
            fuPk.z = pack2(fn[4] * inv_n, fn[5] * inv_n);
            fuPk.w = pack2(fn[6] * inv_n, fn[7] * inv_n);
            *(uint4*)(Pout + (size_t)r * 32 + sl * 4) = fuPk;
        }
        if (lane == 0) nrmOut[r] = nrm;
    }
}

// ---------------------------------------------------------------------------
extern "C" void kernel_launch(void* const* d_in, const int* in_sizes, int n_in,
                              void* d_out, int out_size, void* d_ws, size_t ws_size,
                              hipStream_t stream)
{
    const float* A  = (const float*)d_in[0];
    const float* F  = (const float*)d_in[1];
    const float* W1 = (const float*)d_in[2];
    const float* b1 = (const float*)d_in[3];
    const float* W2 = (const float*)d_in[4];
    const float* b2 = (const float*)d_in[5];
    const float* rg = (const float*)d_in[6];
    float* out = (float*)d_out;

    // workspace layout (~4.6 MB)
    char* p = (char*)d_ws;
    float* F0     = (float*)p; p += (size_t)N_NODES * OUT_DIM * 4;           // 1 MB
    unsigned* Pa  = (unsigned*)p; p += (size_t)N_NODES * 32 * 4;             // 512 KB packed Fu
    unsigned* Pb  = (unsigned*)p; p += (size_t)N_NODES * 32 * 4;             // 512 KB
    float* nrmA   = (float*)p; p += (size_t)N_NODES * 4;                     // 16 KB
    float* nrmB   = (float*)p; p += (size_t)N_NODES * 4;
    float* invD   = (float*)p; p += (size_t)N_NODES * 4;
    float* invDsq = (float*)p; p += (size_t)N_NODES * 4;
    int*   deg    = (int*)p;   p += (size_t)N_NODES * 4;
    int*   ell    = (int*)p;   p += (size_t)N_NODES * MAX_DEG * 4;           // 2 MB

    build_all<<<GEMM_BLOCKS + SCAN_BLOCKS, 256, 0, stream>>>(
        A, F, W1, b1, W2, b2, F0, ell, deg, invD, invDsq);

    // step 0 straight from fp32 F0 (writes Pa/nrmA)
    propagate_f0<<<N_NODES / 4, 256, 0, stream>>>(
        F0, ell, deg, invD, invDsq, rg, Pa, nrmA);

    for (int k = 1; k < PROP_STEP; k++) {
        unsigned* Pin   = (k & 1) ? Pa : Pb;
        unsigned* Pout  = (k & 1) ? Pb : Pa;
        float* nIn      = (k & 1) ? nrmA : nrmB;
        float* nOut     = (k & 1) ? nrmB : nrmA;
        int last = (k == PROP_STEP - 1);
        propagate<<<N_NODES / 4, 256, 0, stream>>>(
            Pin, nIn, F0, ell, deg, invD, invDsq, rg, k,
            Pout, nOut, out, !last, last);
    }
}